// Round 8
// baseline (661.364 us; speedup 1.0000x reference)
//
#include <hip/hip_runtime.h>

// Problem constants (fixed by setup_inputs: H=W=256, WIN=8, NCAV=2, C=256, HEADS=8)
#define NT   64
#define CDIM 256
#define NHEAD 8
#define SCALE 0.17677669529663687f   // hd^-0.5 = 1/sqrt(32)
#define PI_F 3.14159265358979f

typedef short bfrag __attribute__((ext_vector_type(8)));   // 8 bf16 (4 VGPRs)
typedef float f4    __attribute__((ext_vector_type(4)));   // MFMA C/D
typedef unsigned short us4 __attribute__((ext_vector_type(4)));

__device__ __forceinline__ unsigned short f2bf(float f){
  unsigned u = __builtin_bit_cast(unsigned, f);
  u += 0x7FFFu + ((u >> 16) & 1u);       // round-to-nearest-even
  return (unsigned short)(u >> 16);
}
__device__ __forceinline__ unsigned pk2(float a, float b){
  return (unsigned)f2bf(a) | ((unsigned)f2bf(b) << 16);
}
__device__ __forceinline__ f4 mfma16(bfrag a, bfrag b, f4 c){
  return __builtin_amdgcn_mfma_f32_16x16x32_bf16(a, b, c, 0, 0, 0);
}
// swizzle: 64 rows x 32 16B-units/row; unit ^= row&7 -> 2-way (free)
__device__ __forceinline__ int swx(int row, int u){ return (row << 5) + (u ^ (row & 7)); }

// mfma16(A,B) -> C[A's cc-axis on quad*4+r][B's cc-axis on cc]  (proven r1).
// xpose(m0,m1): two stacked C-frags (rows 0-15,16-31 over same cols) ->
// input-frag: lane holds col-axis=cc, row-axis(32) on quad*8+e.  (proven r7)
__device__ __forceinline__ bfrag xpose(f4 m0, f4 m1, int quad, int cc){
  int P0m0 = (int)pk2(m0[0], m0[1]);
  int P1m0 = (int)pk2(m0[2], m0[3]);
  int P0m1 = (int)pk2(m1[0], m1[1]);
  int P1m1 = (int)pk2(m1[2], m1[3]);
  int srcA = ((quad & 1) << 5) + cc;
  int srcB = srcA + 16;
  int hi = quad >> 1;
  int a0 = __shfl(P0m0, srcA, 64), a1 = __shfl(P0m1, srcA, 64);
  int b0 = __shfl(P1m0, srcA, 64), b1 = __shfl(P1m1, srcA, 64);
  int c0 = __shfl(P0m0, srcB, 64), c1 = __shfl(P0m1, srcB, 64);
  int d0 = __shfl(P1m0, srcB, 64), d1 = __shfl(P1m1, srcB, 64);
  union { bfrag f; int u[4]; } r;
  r.u[0] = hi ? a1 : a0;
  r.u[1] = hi ? b1 : b0;
  r.u[2] = hi ? c1 : c0;
  r.u[3] = hi ? d1 : d0;
  return r.f;
}

// 32ch x 32tok sub-GEMM: A = wt rows [ocb,ocb+32), B = x tokens [tb,tb+32) from LDS.
// Returns two bias-added input-layout frags (token tiles tb+0..15, tb+16..31).
__device__ __forceinline__ void subgemm32(const unsigned short* __restrict__ wt,
                                          const unsigned short* lx,
                                          const float* __restrict__ bqkv,
                                          int ocb, int tb, int quad, int cc,
                                          bfrag& f0, bfrag& f1)
{
  f4 acc00 = (f4){0,0,0,0}, acc01 = (f4){0,0,0,0};
  f4 acc10 = (f4){0,0,0,0}, acc11 = (f4){0,0,0,0};
  #pragma unroll
  for (int ks = 0; ks < 8; ++ks){
    bfrag a0 = *(const bfrag*)(wt + (ocb +      cc)*256 + ks*32 + quad*8);
    bfrag a1 = *(const bfrag*)(wt + (ocb + 16 + cc)*256 + ks*32 + quad*8);
    bfrag b0 = *(const bfrag*)(&lx[swx(tb +      cc, ks*4 + quad)*8]);
    bfrag b1 = *(const bfrag*)(&lx[swx(tb + 16 + cc, ks*4 + quad)*8]);
    acc00 = mfma16(a0, b0, acc00);
    acc01 = mfma16(a0, b1, acc01);
    acc10 = mfma16(a1, b0, acc10);
    acc11 = mfma16(a1, b1, acc11);
  }
  #pragma unroll
  for (int r = 0; r < 4; ++r){
    float bb0 = bqkv[ocb +      quad*4 + r];
    float bb1 = bqkv[ocb + 16 + quad*4 + r];
    acc00[r] += bb0; acc01[r] += bb0;
    acc10[r] += bb1; acc11[r] += bb1;
  }
  f0 = xpose(acc00, acc10, quad, cc);
  f1 = xpose(acc01, acc11, quad, cc);
}

// ---------------------------------------------------------------------------
// Prep: bf16 W^T (q-scaled) + fused qkv bias. rel/ego computed in-kernel.
// ---------------------------------------------------------------------------
__global__ void prep_kernel(const float* __restrict__ Wq,  const float* __restrict__ bq,
                            const float* __restrict__ Wkv, const float* __restrict__ bkv,
                            const float* __restrict__ Wp,
                            unsigned short* __restrict__ wt, float* __restrict__ bqkv)
{
  const int bid = blockIdx.x, tid = threadIdx.x;
  if (bid < 256) {                        // tiled weight transpose + bf16
    __shared__ float t[32][33];
    const int r0 = (bid >> 3) * 32;
    const int c0 = (bid & 7) * 32;
    const int rl = tid & 31, ch = tid >> 5;
    for (int k = 0; k < 4; ++k){
      int c = c0 + ch + k*8, r = r0 + rl;
      float v;
      if (r < 256)      v = Wq[c*256 + r] * SCALE;
      else if (r < 768) v = Wkv[c*512 + (r - 256)];
      else              v = Wp[c*256 + (r - 768)];
      t[rl][ch + k*8] = v;
    }
    __syncthreads();
    for (int k = 0; k < 4; ++k){
      int orr = ch + k*8;
      wt[(r0 + orr)*256 + c0 + rl] = f2bf(t[orr][rl]);
    }
  } else {                                // fused qkv bias (q part scaled)
    for (int j = tid; j < 768; j += 256)
      bqkv[j] = (j < 256) ? bq[j]*SCALE : bkv[j - 256];
  }
}

// ---------------------------------------------------------------------------
// Fused window attention: one block per window, 512 threads (8 waves),
// ONE HEAD PER WAVE. q,k,v all in REGISTER frags (48 VGPR); softmax per-lane
// (attn2 structure, verified r7); P and y produced in-register via xpose.
// Single 32 KiB LDS buffer: x (swizzled) -> y frag blob. 3 barriers.
// No register array is ever passed by pointer (rule-20 scratch trap).
// ---------------------------------------------------------------------------
__global__ __launch_bounds__(512, 4) void attn_kernel(
    const float* __restrict__ x, const float* __restrict__ wvec,
    const float* __restrict__ bp, float* __restrict__ out,
    const unsigned short* __restrict__ wt, const float* __restrict__ bqkv,
    const float* __restrict__ relt, const float* __restrict__ egot,
    const float* __restrict__ aff)
{
  __shared__ unsigned short ldsX[NT*CDIM];       // 32 KiB: x -> y blob

  const int b = blockIdx.x;
  const int tid = threadIdx.x;
  const int wv = tid >> 6, lane = tid & 63;
  const int quad = lane >> 4, cc = lane & 15;
  const int h = wv;                              // one head per wave

  // ---- stage x window -> bf16 ldsX (swizzled) ----
  const float4* xg = (const float4*)(x + (size_t)b*(NT*CDIM));
  #pragma unroll
  for (int it = 0; it < 8; ++it){
    int i4 = tid + it*512;
    float4 v = xg[i4];
    us4 pk = { f2bf(v.x), f2bf(v.y), f2bf(v.z), f2bf(v.w) };
    int row = i4 >> 6, u = (i4 & 63) >> 1, hf = i4 & 1;
    *(us4*)(&ldsX[swx(row, u)*8 + hf*4]) = pk;
  }
  // blend weights + ego bias (closed-form dmax over the 4 grid corners; r6-verified)
  float w0 = wvec[0], w1 = wvec[1];
  float wm = fmaxf(w0, w1);
  float e0 = __expf(w0 - wm), e1 = __expf(w1 - wm);
  float ws0 = e0/(e0+e1), ws1 = e1/(e0+e1);
  float ego;
  {
    float ex0=(aff[0]+aff[1])*128.f+aff[2],  ey0=(aff[3]+aff[4])*128.f+aff[5];
    float ex1=(aff[6]+aff[7])*128.f+aff[8],  ey1=(aff[9]+aff[10])*128.f+aff[11];
    float dmax = 0.f;
    #pragma unroll
    for (int c = 0; c < 4; ++c){
      float cx = (c & 1) ? 252.f : 4.f, cy = (c >> 1) ? 252.f : 4.f;
      float d0x=cx-ex0, d0y=cy-ey0, d1x=cx-ex1, d1y=cy-ey1;
      dmax = fmaxf(dmax, fmaxf(sqrtf(d0x*d0x+d0y*d0y), sqrtf(d1x*d1x+d1y*d1y)));
    }
    dmax += 1e-6f;
    int cv = b >> 10, wi = b & 1023;
    float cx = (float)((wi & 31)*8 + 4), cy = (float)((wi >> 5)*8 + 4);
    float ex = cv ? ex1 : ex0, ey = cv ? ey1 : ey0;
    float dx = cx - ex, dy = cy - ey;
    float dd = sqrtf(dx*dx + dy*dy);
    float ang = atan2f(dy, dx);
    int db = (int)(dd/dmax*3.0f);
    int ab = (int)((ang + PI_F)/(2.0f*PI_F)*3.0f);
    ego = egot[(db*4 + ab)*8 + h];
  }
  __syncthreads();                               // b0: x staged

  // ---- phase 1 (wave-local): q,k A-frags + v^T B-frags, all in registers ----
  bfrag qf[4], kf[4], vf[4];
  subgemm32(wt, ldsX, bqkv, h*32,       0,  quad, cc, qf[0], qf[1]);
  subgemm32(wt, ldsX, bqkv, h*32,       32, quad, cc, qf[2], qf[3]);
  subgemm32(wt, ldsX, bqkv, 256 + h*32, 0,  quad, cc, kf[0], kf[1]);
  subgemm32(wt, ldsX, bqkv, 256 + h*32, 32, quad, cc, kf[2], kf[3]);
  // v with swapped operands: C'[tok][oc] so xpose yields v^T frags [d][ktok]
  #pragma unroll
  for (int chunk = 0; chunk < 2; ++chunk){
    int tb = chunk*32;
    f4 acc00 = (f4){0,0,0,0}, acc01 = (f4){0,0,0,0};
    f4 acc10 = (f4){0,0,0,0}, acc11 = (f4){0,0,0,0};
    #pragma unroll
    for (int ks = 0; ks < 8; ++ks){
      bfrag x0 = *(const bfrag*)(&ldsX[swx(tb +      cc, ks*4 + quad)*8]);
      bfrag x1 = *(const bfrag*)(&ldsX[swx(tb + 16 + cc, ks*4 + quad)*8]);
      bfrag w0f = *(const bfrag*)(wt + (512 + h*32 +      cc)*256 + ks*32 + quad*8);
      bfrag w1f = *(const bfrag*)(wt + (512 + h*32 + 16 + cc)*256 + ks*32 + quad*8);
      acc00 = mfma16(x0, w0f, acc00);
      acc01 = mfma16(x0, w1f, acc01);
      acc10 = mfma16(x1, w0f, acc10);
      acc11 = mfma16(x1, w1f, acc11);
    }
    float bb0 = bqkv[512 + h*32 +      cc];      // bias along oc = cc axis
    float bb1 = bqkv[512 + h*32 + 16 + cc];
    #pragma unroll
    for (int r = 0; r < 4; ++r){
      acc00[r] += bb0; acc10[r] += bb0;
      acc01[r] += bb1; acc11[r] += bb1;
    }
    vf[chunk*2 + 0] = xpose(acc00, acc10, quad, cc);   // d 0-15 half? (r7 layout)
    vf[chunk*2 + 1] = xpose(acc01, acc11, quad, cc);
  }
  __syncthreads();                               // b1: all x reads done

  // ---- phase 2 (attn2 body, verified r7): S^T -> softmax -> P -> y frags ----
  const f4 z4 = (f4){0,0,0,0};
  #pragma unroll
  for (int qt = 0; qt < 4; ++qt){
    f4 SA[4];                                    // S^T[ktok on kt,quad*4+r][qtok=cc]
    #pragma unroll
    for (int kt = 0; kt < 4; ++kt) SA[kt] = mfma16(kf[kt], qf[qt], z4);
    int ii = qt*16 + cc;                         // query token (per lane)
    int yi = ii >> 3, xi = ii & 7;
    #pragma unroll
    for (int kt = 0; kt < 4; ++kt)
      #pragma unroll
      for (int r = 0; r < 4; ++r){
        int jj = kt*16 + quad*4 + r;             // key token
        int ridx = (yi - (jj >> 3) + 7)*15 + (xi - (jj & 7) + 7);
        SA[kt][r] += relt[ridx*8 + h] + ego;
      }
    float m = -1e30f;
    #pragma unroll
    for (int kt = 0; kt < 4; ++kt)
      #pragma unroll
      for (int r = 0; r < 4; ++r) m = fmaxf(m, SA[kt][r]);
    m = fmaxf(m, __shfl_xor(m, 16, 64));
    m = fmaxf(m, __shfl_xor(m, 32, 64));
    float s = 0.0f;
    #pragma unroll
    for (int kt = 0; kt < 4; ++kt)
      #pragma unroll
      for (int r = 0; r < 4; ++r) s += __expf(SA[kt][r] - m);
    s += __shfl_xor(s, 16, 64);
    s += __shfl_xor(s, 32, 64);
    float Z = m + __logf(s);
    #pragma unroll
    for (int kt = 0; kt < 4; ++kt)
      #pragma unroll
      for (int r = 0; r < 4; ++r){
        float av = SA[kt][r];
        float rl = fmaxf(av, 0.0f);
        SA[kt][r] = ws0 * __expf(av - Z) + ws1 * rl * rl;
      }
    bfrag p0 = xpose(SA[0], SA[1], quad, cc);    // P A-frag, ktok chunk 0
    bfrag p1 = xpose(SA[2], SA[3], quad, cc);    // chunk 1
    f4 yT0 = mfma16(vf[0], p0, z4); yT0 = mfma16(vf[2], p1, yT0);  // d 0-15
    f4 yT1 = mfma16(vf[1], p0, z4); yT1 = mfma16(vf[3], p1, yT1);  // d 16-31
    bfrag yf = xpose(yT0, yT1, quad, cc);        // y A-frag [qtok=cc][d 0-31]
    *(bfrag*)(&ldsX[((qt*8 + h)*64 + lane)*8]) = yf;
  }
  __syncthreads();                               // b2: y blob staged

  // ---- phase 3 (proj body, verified r7): out = y @ Wp + bp ----
  {
    const int mt = wv & 3;                       // token tile
    const int cb = (wv >> 2)*128;                // 2 col halves
    f4 o[8];
    #pragma unroll
    for (int nt = 0; nt < 8; ++nt) o[nt] = (f4){0,0,0,0};
    #pragma unroll
    for (int ks = 0; ks < 8; ++ks){
      bfrag ay = *(const bfrag*)(&ldsX[((mt*8 + ks)*64 + lane)*8]);
      #pragma unroll
      for (int nt = 0; nt < 8; ++nt){
        bfrag bw = *(const bfrag*)(wt + (768 + cb + nt*16 + cc)*256 + ks*32 + quad*8);
        o[nt] = mfma16(ay, bw, o[nt]);
      }
    }
    float* og = out + (size_t)b*(NT*CDIM);
    #pragma unroll
    for (int nt = 0; nt < 8; ++nt){
      int col = cb + nt*16 + cc;
      float bpv = bp[col];
      #pragma unroll
      for (int r = 0; r < 4; ++r){
        int tok = mt*16 + quad*4 + r;
        og[tok*256 + col] = o[nt][r] + bpv;
      }
    }
  }
}

extern "C" void kernel_launch(void* const* d_in, const int* in_sizes, int n_in,
                              void* d_out, int out_size, void* d_ws, size_t ws_size,
                              hipStream_t stream)
{
  const float* x    = (const float*)d_in[0];
  const float* aff  = (const float*)d_in[1];
  const float* Wq   = (const float*)d_in[2];
  const float* bq   = (const float*)d_in[3];
  const float* Wkv  = (const float*)d_in[4];
  const float* bkv  = (const float*)d_in[5];
  const float* Wp   = (const float*)d_in[6];
  const float* bp   = (const float*)d_in[7];
  const float* relt = (const float*)d_in[8];
  const float* egot = (const float*)d_in[9];
  const float* w    = (const float*)d_in[10];
  float* out = (float*)d_out;

  char* ws = (char*)d_ws;
  unsigned short* wt = (unsigned short*)ws;       // 512 KiB bf16 W^T
  float* bqkv = (float*)(ws + 524288);            //   3 KiB

  hipLaunchKernelGGL(prep_kernel, dim3(257), dim3(256), 0, stream,
                     Wq, bq, Wkv, bkv, Wp, wt, bqkv);
  hipLaunchKernelGGL(attn_kernel, dim3(2048), dim3(512), 0, stream,
                     x, w, bp, out, wt, bqkv, relt, egot, aff);
}